// Round 8
// baseline (1043.501 us; speedup 1.0000x reference)
//
#include <hip/hip_runtime.h>
#include <math.h>

#define BATCH 64
#define SEQ 300
#define DM 1024
#define DP 128
#define NH 4
#define NC 3862
#define MROWS (BATCH*SEQ)   // 19200
#define NSTK (6*DP)         // 768: [K | V | Q0..Q3]

#define BM 128
#define BN 128
#define BK 16

typedef double d4 __attribute__((ext_vector_type(4)));

// ---------------------------------------------------------------------------
// Kernel 1: fused QKV projection GEMM on the f64 MFMA pipe.
// C = X * W^T + bias, exact f64 accumulation (argmax-tie safety).
// Grid (150, 6); block 256 = 4 waves in 2x2; wave tile 64x64 (16 MFMA tiles).
// Async global_load_lds double-buffered staging (validated bit-exact r3/r4).
// f64 MFMA layouts (HW-confirmed r7 PASS): A: i=lane&15, k=lane>>4;
// B: j=lane&15, k=lane>>4; D: row = (lane>>4) + 4*reg, col = lane&15.
// Fragment reads: ds_read_b128 with 4-lane same-address broadcast per
// g-group (kills the r7 8-way bank conflict, 1.03e8 conflict cycles), then
// 3x v_cndmask component-extract per element (VALU pipe, 7% busy, free).
// ---------------------------------------------------------------------------
__global__ __launch_bounds__(256, 2) void proj_gemm_mfma(
    const float* __restrict__ X,
    const float* __restrict__ Wk, const float* __restrict__ bk,
    const float* __restrict__ Wv, const float* __restrict__ bv,
    const float* __restrict__ Wq, const float* __restrict__ bq,
    float* __restrict__ O)
{
    const int mtile = blockIdx.x;   // 0..149
    const int wsel  = blockIdx.y;   // 0..5 : K,V,Q0..Q3

    const float* Wbase; const float* bias;
    if (wsel == 0)      { Wbase = Wk; bias = bk; }
    else if (wsel == 1) { Wbase = Wv; bias = bv; }
    else                { Wbase = Wq + (size_t)(wsel - 2) * DP * DM;
                          bias  = bq + (wsel - 2) * DP; }

    // [row][k] linear f32 tiles -- exactly the lane-linear order
    // global_load_lds writes (slot s -> row s>>2, k (s&3)*4..+3).
    __shared__ float As[2][BM * BK];
    __shared__ float Bs[2][BN * BK];

    const int tid  = threadIdx.x;
    const int lane = tid & 63;
    const int wave = tid >> 6;
    const int wm = wave >> 1, wn = wave & 1;   // 2x2 wave grid
    const int mbase = mtile * BM;

    const int r = lane & 15;   // A row / B col / D col within 16-tile
    const int g = lane >> 4;   // k-subindex (0..3) for A/B; D row base
    const bool s0 = (g & 1) != 0;
    const bool s1 = (g & 2) != 0;

    d4 acc[4][4];
    #pragma unroll
    for (int mt = 0; mt < 4; ++mt)
        #pragma unroll
        for (int nt = 0; nt < 4; ++nt)
            acc[mt][nt] = (d4)(0.0);

    // ---- async staging: one tile = 512 16B-slots (A) + 512 (B); each wave
    // issues 2 A-slabs + 2 B-slabs of 64 lanes x 16B.
#define STAGE(bufi, k0)                                                        \
    do {                                                                       \
        _Pragma("unroll")                                                      \
        for (int j = 0; j < 2; ++j) {                                          \
            const int slotbase = wave * 128 + j * 64;   /* wave-uniform */     \
            const int slot = slotbase + lane;                                  \
            const int mrow = slot >> 2;                                        \
            const int kq4  = (slot & 3) << 2;                                  \
            const float* srcA = &X[(size_t)(mbase + mrow) * DM + (k0) + kq4];  \
            __builtin_amdgcn_global_load_lds(                                  \
                (const __attribute__((address_space(1))) void*)srcA,           \
                (__attribute__((address_space(3))) void*)&As[bufi][slotbase * 4], \
                16, 0, 0);                                                     \
            const float* srcB = &Wbase[(size_t)mrow * DM + (k0) + kq4];        \
            __builtin_amdgcn_global_load_lds(                                  \
                (const __attribute__((address_space(1))) void*)srcB,           \
                (__attribute__((address_space(3))) void*)&Bs[bufi][slotbase * 4], \
                16, 0, 0);                                                     \
        }                                                                      \
    } while (0)

    STAGE(0, 0);
    __syncthreads();   // drains vmcnt -> buf0 ready

    int buf = 0;
    for (int t = 0; t < DM / BK; ++t) {
        if (t + 1 < DM / BK) {
            if (buf == 0) STAGE(1, (t + 1) * BK);
            else          STAGE(0, (t + 1) * BK);
        }
        // compute on As[buf]/Bs[buf]; 4 MFMA k-steps (K=4 each) x 16 tiles.
        // b128 broadcast read (same addr across the 4 lanes of a g-group),
        // then component-select g via cndmask -> f64.
        #pragma unroll
        for (int kq = 0; kq < 4; ++kq) {
            double a[4], b[4];
            #pragma unroll
            for (int mt = 0; mt < 4; ++mt) {
                const float4 v = *reinterpret_cast<const float4*>(
                    &As[buf][(wm * 64 + mt * 16 + r) * BK + kq * 4]);
                const float lo = s0 ? v.y : v.x;
                const float hi = s0 ? v.w : v.z;
                a[mt] = (double)(s1 ? hi : lo);
            }
            #pragma unroll
            for (int nt = 0; nt < 4; ++nt) {
                const float4 v = *reinterpret_cast<const float4*>(
                    &Bs[buf][(wn * 64 + nt * 16 + r) * BK + kq * 4]);
                const float lo = s0 ? v.y : v.x;
                const float hi = s0 ? v.w : v.z;
                b[nt] = (double)(s1 ? hi : lo);
            }
            #pragma unroll
            for (int mt = 0; mt < 4; ++mt)
                #pragma unroll
                for (int nt = 0; nt < 4; ++nt)
                    acc[mt][nt] = __builtin_amdgcn_mfma_f64_16x16x4f64(
                        a[mt], b[nt], acc[mt][nt], 0, 0, 0);
        }
        __syncthreads();   // drains next-tile loads; guards LDS reuse
        buf ^= 1;
    }
#undef STAGE

    // epilogue: D[row = g + 4*i][col = r] per 16x16 tile (f64 reg-strided)
    #pragma unroll
    for (int nt = 0; nt < 4; ++nt) {
        const int col = wn * 64 + nt * 16 + r;
        const double bi = (double)bias[col];
        #pragma unroll
        for (int mt = 0; mt < 4; ++mt) {
            #pragma unroll
            for (int i = 0; i < 4; ++i) {
                const int row = wm * 64 + mt * 16 + g + 4 * i;
                O[(size_t)(mbase + row) * NSTK + wsel * DP + col] =
                    (float)(acc[mt][nt][i] + bi);
            }
        }
    }
}

// ---------------------------------------------------------------------------
// Kernel 2: attention per (b,h), all math in f64.
// ---------------------------------------------------------------------------
__global__ __launch_bounds__(256) void attn_kernel(
    const float* __restrict__ QKV,
    float* __restrict__ scores_out,  // [B][S][H] f32
    float* __restrict__ attnw_out,   // [B][S][H] f32
    double* __restrict__ wsrelu)     // [B][H][DP] f64
{
    const int b = blockIdx.x >> 2;
    const int h = blockIdx.x & 3;
    const int tid = threadIdx.x;
    const int wave = tid >> 6, lane = tid & 63;

    __shared__ double sc[SEQ];
    __shared__ double red[4];
    __shared__ double wacc[2][DP];

    const double scale = 0.08838834764831843;  // 1/sqrt(128) (f64)
    const float* base = QKV + (size_t)b * SEQ * NSTK;

    // scores: one wave per s
    for (int s = wave; s < SEQ; s += 4) {
        const float* row = base + (size_t)s * NSTK;
        const float2 qv = *reinterpret_cast<const float2*>(row + 256 + h * DP + lane * 2);
        const float2 kv = *reinterpret_cast<const float2*>(row + lane * 2);
        double p = (double)qv.x * (double)kv.x + (double)qv.y * (double)kv.y;
        #pragma unroll
        for (int o = 32; o; o >>= 1) p += __shfl_xor(p, o);
        p *= scale;
        if (lane == 0) {
            sc[s] = p;
            scores_out[((size_t)b * SEQ + s) * NH + h] = (float)p;
        }
    }
    __syncthreads();

    // softmax max
    double mx = -1e300;
    for (int i = tid; i < SEQ; i += 256) mx = fmax(mx, sc[i]);
    #pragma unroll
    for (int o = 32; o; o >>= 1) mx = fmax(mx, __shfl_xor(mx, o));
    if (lane == 0) red[wave] = mx;
    __syncthreads();
    mx = fmax(fmax(red[0], red[1]), fmax(red[2], red[3]));
    __syncthreads();

    double lsum = 0.0;
    for (int i = tid; i < SEQ; i += 256) {
        const double e = exp(sc[i] - mx);
        sc[i] = e;
        lsum += e;
    }
    #pragma unroll
    for (int o = 32; o; o >>= 1) lsum += __shfl_xor(lsum, o);
    if (lane == 0) red[wave] = lsum;
    __syncthreads();
    const double inv = 1.0 / (red[0] + red[1] + red[2] + red[3]);
    __syncthreads();
    for (int i = tid; i < SEQ; i += 256) {
        const double p = sc[i] * inv;
        sc[i] = p;
        attnw_out[((size_t)b * SEQ + i) * NH + h] = (float)p;
    }
    __syncthreads();

    // ws[p] = sum_s p_attn[s] * vals[s][p]
    const int p_idx = tid & 127, half = tid >> 7;
    double acc = 0.0;
    for (int s = half; s < SEQ; s += 2)
        acc = fma(sc[s], (double)base[(size_t)s * NSTK + 128 + p_idx], acc);
    wacc[half][p_idx] = acc;
    __syncthreads();
    if (tid < DP) {
        const double w = wacc[0][tid] + wacc[1][tid];
        wsrelu[((size_t)b * NH + h) * DP + tid] = fmax(w, 0.0);
    }
}

// ---------------------------------------------------------------------------
// Kernel 3a: logits[bh][c] = relu_ws . Wc[c] + bc[c] (f64); per-row mean/std.
// ---------------------------------------------------------------------------
__global__ __launch_bounds__(256) void logits_kernel(
    const double* __restrict__ wsrelu, const float* __restrict__ Wc,
    const float* __restrict__ bc, double* __restrict__ logits,
    double* __restrict__ stats)
{
    const int bh = blockIdx.x;
    const int tid = threadIdx.x;
    const int wave = tid >> 6, lane = tid & 63;
    __shared__ double w4s[DP];
    __shared__ double red[4];
    if (tid < DP) w4s[tid] = wsrelu[(size_t)bh * DP + tid];
    __syncthreads();

    double lsum = 0.0;
    for (int c = tid; c < NC; c += 256) {
        const float4* wr = reinterpret_cast<const float4*>(Wc + (size_t)c * DP);
        double acc = 0.0;
        #pragma unroll
        for (int k = 0; k < 32; ++k) {
            const float4 v = wr[k];
            acc = fma((double)v.x, w4s[4 * k + 0], acc);
            acc = fma((double)v.y, w4s[4 * k + 1], acc);
            acc = fma((double)v.z, w4s[4 * k + 2], acc);
            acc = fma((double)v.w, w4s[4 * k + 3], acc);
        }
        acc += (double)bc[c];
        logits[(size_t)bh * NC + c] = acc;
        lsum += acc;
    }
    #pragma unroll
    for (int o = 32; o; o >>= 1) lsum += __shfl_xor(lsum, o);
    if (lane == 0) red[wave] = lsum;
    __syncthreads();
    const double mean = (red[0] + red[1] + red[2] + red[3]) / (double)NC;
    __syncthreads();

    double lss = 0.0;
    for (int c = tid; c < NC; c += 256) {
        const double d = logits[(size_t)bh * NC + c] - mean;
        lss = fma(d, d, lss);
    }
    #pragma unroll
    for (int o = 32; o; o >>= 1) lss += __shfl_xor(lss, o);
    if (lane == 0) red[wave] = lss;
    __syncthreads();
    if (tid == 0) {
        const double var = (red[0] + red[1] + red[2] + red[3]) / (double)(NC - 1);
        stats[bh * 2 + 0] = mean;
        stats[bh * 2 + 1] = sqrt(var);
    }
}

// ---------------------------------------------------------------------------
// Kernel 3b: LN + max/argmax over heads + sigmoid, f64 compare path.
// ---------------------------------------------------------------------------
__global__ __launch_bounds__(256) void finalize_kernel(
    const double* __restrict__ logits, const double* __restrict__ stats,
    const float* __restrict__ ln_a, const float* __restrict__ ln_b,
    float* __restrict__ vid_probs, float* __restrict__ attn_idc)
{
    const int c = blockIdx.x * 256 + threadIdx.x;
    const int b = blockIdx.y;
    if (c >= NC) return;
    const double a = (double)ln_a[c], bb = (double)ln_b[c];
    double best = -1e300;
    int bi = 0;
    #pragma unroll
    for (int h = 0; h < NH; ++h) {
        const int bh = b * NH + h;
        const double x = logits[(size_t)bh * NC + c];
        const double ln = a * (x - stats[bh * 2]) / (stats[bh * 2 + 1] + 1e-6) + bb;
        if (ln > best) { best = ln; bi = h; }
    }
    vid_probs[(size_t)b * NC + c] = (float)(1.0 / (1.0 + exp(-best)));
    attn_idc[(size_t)b * NC + c] = (float)bi;
}

// ---------------------------------------------------------------------------
// Kernel 4: conv regularizer loss (Wc, bc only), f64. One block.
// ---------------------------------------------------------------------------
__global__ __launch_bounds__(256) void convloss_kernel(
    const float* __restrict__ Wc, const float* __restrict__ bc,
    float* __restrict__ out)
{
    __shared__ double t[NC];
    __shared__ double red[4];
    const int tid = threadIdx.x;
    const int wave = tid >> 6, lane = tid & 63;

    double lmax = -1e300;
    for (int c = tid; c < NC; c += 256) {
        const float4* wr = reinterpret_cast<const float4*>(Wc + (size_t)c * DP);
        double acc = 0.0;
        #pragma unroll
        for (int k = 0; k < 32; ++k) {
            const float4 v = wr[k];
            acc += (double)v.x + (double)v.y + (double)v.z + (double)v.w;
        }
        acc += (double)bc[c];
        t[c] = acc;
        lmax = fmax(lmax, acc);
    }
    #pragma unroll
    for (int o = 32; o; o >>= 1) lmax = fmax(lmax, __shfl_xor(lmax, o));
    if (lane == 0) red[wave] = lmax;
    __syncthreads();
    const double mx = fmax(fmax(red[0], red[1]), fmax(red[2], red[3]));
    __syncthreads();

    double lsum = 0.0;
    for (int c = tid; c < NC; c += 256) {
        const double e = exp(t[c] - mx);
        t[c] = e;
        lsum += e;
    }
    #pragma unroll
    for (int o = 32; o; o >>= 1) lsum += __shfl_xor(lsum, o);
    if (lane == 0) red[wave] = lsum;
    __syncthreads();
    const double inv = 1.0 / (red[0] + red[1] + red[2] + red[3]);
    __syncthreads();

    double psum = 0.0;
    for (int c = tid; c < NC; c += 256) {
        const double p = t[c] * inv;
        t[c] = p;
        psum += p;
    }
    #pragma unroll
    for (int o = 32; o; o >>= 1) psum += __shfl_xor(psum, o);
    if (lane == 0) red[wave] = psum;
    __syncthreads();
    const double mean = (red[0] + red[1] + red[2] + red[3]) / (double)NC;
    __syncthreads();

    double lss = 0.0;
    for (int c = tid; c < NC; c += 256) {
        const double d = t[c] - mean;
        lss = fma(d, d, lss);
    }
    #pragma unroll
    for (int o = 32; o; o >>= 1) lss += __shfl_xor(lss, o);
    if (lane == 0) red[wave] = lss;
    __syncthreads();
    if (tid == 0) {
        double stdv = sqrt((red[0] + red[1] + red[2] + red[3]) / (double)(NC - 1));
        stdv = fmin(fmax(stdv, 1e-9), 1e9);
        out[0] = (float)((double)BATCH * stdv);
    }
}

// ---------------------------------------------------------------------------
extern "C" void kernel_launch(void* const* d_in, const int* in_sizes, int n_in,
                              void* d_out, int out_size, void* d_ws, size_t ws_size,
                              hipStream_t stream)
{
    (void)in_sizes; (void)n_in; (void)out_size; (void)ws_size;
    const float* seg  = (const float*)d_in[0];
    const float* Wq   = (const float*)d_in[1];
    const float* bq   = (const float*)d_in[2];
    const float* Wk   = (const float*)d_in[3];
    const float* bk   = (const float*)d_in[4];
    const float* Wv   = (const float*)d_in[5];
    const float* bv   = (const float*)d_in[6];
    const float* Wc   = (const float*)d_in[7];
    const float* bc   = (const float*)d_in[8];
    const float* ln_a = (const float*)d_in[9];
    const float* ln_b = (const float*)d_in[10];

    float* out = (float*)d_out;
    float* vid_probs = out;                           // 64*3862
    float* attn_idc  = out + (size_t)BATCH * NC;      // 64*3862
    float* scores    = attn_idc + (size_t)BATCH * NC; // 64*300*4
    float* attnw     = scores + (size_t)BATCH * SEQ * NH;
    float* convl     = attnw + (size_t)BATCH * SEQ * NH;

    char* wsp = (char*)d_ws;
    float*  QKV    = (float*)wsp;                              // 19200*768 f32 (59.0 MB)
    wsp += (size_t)MROWS * NSTK * sizeof(float);
    double* wsrelu = (double*)wsp;                             // 256*128 f64
    wsp += (size_t)BATCH * NH * DP * sizeof(double);
    double* logits = (double*)wsp;                             // 256*3862 f64 (7.9 MB)
    wsp += (size_t)BATCH * NH * NC * sizeof(double);
    double* stats  = (double*)wsp;                             // 256*2 f64

    dim3 g1(MROWS / BM, NSTK / BN);   // (150, 6)
    proj_gemm_mfma<<<g1, 256, 0, stream>>>(seg, Wk, bk, Wv, bv, Wq, bq, QKV);

    attn_kernel<<<BATCH * NH, 256, 0, stream>>>(QKV, scores, attnw, wsrelu);

    logits_kernel<<<BATCH * NH, 256, 0, stream>>>(wsrelu, Wc, bc, logits, stats);

    dim3 g3((NC + 255) / 256, BATCH);
    finalize_kernel<<<g3, 256, 0, stream>>>(logits, stats, ln_a, ln_b, vid_probs, attn_idc);

    convloss_kernel<<<1, 256, 0, stream>>>(Wc, bc, convl);
}

// Round 9
// 850.071 us; speedup vs baseline: 1.2275x; 1.2275x over previous
//
#include <hip/hip_runtime.h>
#include <math.h>

#define BATCH 64
#define SEQ 300
#define DM 1024
#define DP 128
#define NH 4
#define NC 3862
#define MROWS (BATCH*SEQ)   // 19200
#define NSTK (6*DP)         // 768: [K | V | Q0..Q3]

#define BM 128
#define BN 128
#define BK 16

typedef double d4 __attribute__((ext_vector_type(4)));

// ---------------------------------------------------------------------------
// Kernel 1: fused QKV projection GEMM on the f64 MFMA pipe.
// C = X * W^T + bias, exact f64 accumulation (argmax-tie safety).
// Grid (150, 6); block 256 = 4 waves in 2x2; wave tile 64x64 (16 MFMA tiles).
// Async global_load_lds double-buffered staging (validated bit-exact r3/r4).
// f64 MFMA layouts (HW-confirmed r7 PASS): A: i=lane&15, k=lane>>4;
// B: j=lane&15, k=lane>>4; D: row = (lane>>4) + 4*reg, col = lane&15.
//
// Bank-conflict fix (r8 post-mortem): row stride 64B => rows alias banks
// mod 2; scalar fragment reads at row*16 + kq*4 + g collide 8-way across r
// (1.03e8 conflict cycles in r7). Fix: XOR-swizzle the k-granule on BOTH
// sides (rule #21): granule kq' = kq ^ ((row>>2)&3). STAGE pre-swizzles the
// global source address (LDS dest stays linear for global_load_lds); reads
// apply the same XOR. Read banks become 16(r&1)+4(kq^((r>>2)&3))+g -> every
// bank hit by exactly 2 lanes = free (m136).
// ---------------------------------------------------------------------------
__global__ __launch_bounds__(256, 2) void proj_gemm_mfma(
    const float* __restrict__ X,
    const float* __restrict__ Wk, const float* __restrict__ bk,
    const float* __restrict__ Wv, const float* __restrict__ bv,
    const float* __restrict__ Wq, const float* __restrict__ bq,
    float* __restrict__ O)
{
    const int mtile = blockIdx.x;   // 0..149
    const int wsel  = blockIdx.y;   // 0..5 : K,V,Q0..Q3

    const float* Wbase; const float* bias;
    if (wsel == 0)      { Wbase = Wk; bias = bk; }
    else if (wsel == 1) { Wbase = Wv; bias = bv; }
    else                { Wbase = Wq + (size_t)(wsel - 2) * DP * DM;
                          bias  = bq + (wsel - 2) * DP; }

    // [row][k] linear f32 tiles; slot s holds global granule
    // (row = s>>2, kq = (s&3) ^ ((row>>2)&3)).
    __shared__ float As[2][BM * BK];
    __shared__ float Bs[2][BN * BK];

    const int tid  = threadIdx.x;
    const int lane = tid & 63;
    const int wave = tid >> 6;
    const int wm = wave >> 1, wn = wave & 1;   // 2x2 wave grid
    const int mbase = mtile * BM;

    const int r = lane & 15;   // A row / B col / D col within 16-tile
    const int g = lane >> 4;   // k-subindex (0..3) for A/B; D row base
    const int sw = (r >> 2) & 3;   // per-lane XOR swizzle key

    d4 acc[4][4];
    #pragma unroll
    for (int mt = 0; mt < 4; ++mt)
        #pragma unroll
        for (int nt = 0; nt < 4; ++nt)
            acc[mt][nt] = (d4)(0.0);

    // ---- async staging: one tile = 512 16B-slots (A) + 512 (B); each wave
    // issues 2 A-slabs + 2 B-slabs of 64 lanes x 16B. Global source granule
    // is pre-swizzled; LDS destination stays linear (wave-uniform base).
#define STAGE(bufi, k0)                                                        \
    do {                                                                       \
        _Pragma("unroll")                                                      \
        for (int j = 0; j < 2; ++j) {                                          \
            const int slotbase = wave * 128 + j * 64;   /* wave-uniform */     \
            const int slot = slotbase + lane;                                  \
            const int mrow = slot >> 2;                                        \
            const int kq4  = (((slot & 3) ^ ((mrow >> 2) & 3))) << 2;          \
            const float* srcA = &X[(size_t)(mbase + mrow) * DM + (k0) + kq4];  \
            __builtin_amdgcn_global_load_lds(                                  \
                (const __attribute__((address_space(1))) void*)srcA,           \
                (__attribute__((address_space(3))) void*)&As[bufi][slotbase * 4], \
                16, 0, 0);                                                     \
            const float* srcB = &Wbase[(size_t)mrow * DM + (k0) + kq4];        \
            __builtin_amdgcn_global_load_lds(                                  \
                (const __attribute__((address_space(1))) void*)srcB,           \
                (__attribute__((address_space(3))) void*)&Bs[bufi][slotbase * 4], \
                16, 0, 0);                                                     \
        }                                                                      \
    } while (0)

    STAGE(0, 0);
    __syncthreads();   // drains vmcnt -> buf0 ready

    int buf = 0;
    for (int t = 0; t < DM / BK; ++t) {
        if (t + 1 < DM / BK) {
            if (buf == 0) STAGE(1, (t + 1) * BK);
            else          STAGE(0, (t + 1) * BK);
        }
        // compute on As[buf]/Bs[buf]; 4 MFMA k-steps (K=4 each) x 16 tiles.
        // Scalar b32 fragment reads with the same XOR swizzle -> 2-way (free).
        #pragma unroll
        for (int kq = 0; kq < 4; ++kq) {
            const int kqs = ((kq ^ sw) << 2) + g;
            double a[4], b[4];
            #pragma unroll
            for (int mt = 0; mt < 4; ++mt)
                a[mt] = (double)As[buf][(wm * 64 + mt * 16 + r) * BK + kqs];
            #pragma unroll
            for (int nt = 0; nt < 4; ++nt)
                b[nt] = (double)Bs[buf][(wn * 64 + nt * 16 + r) * BK + kqs];
            #pragma unroll
            for (int mt = 0; mt < 4; ++mt)
                #pragma unroll
                for (int nt = 0; nt < 4; ++nt)
                    acc[mt][nt] = __builtin_amdgcn_mfma_f64_16x16x4f64(
                        a[mt], b[nt], acc[mt][nt], 0, 0, 0);
        }
        __syncthreads();   // drains next-tile loads; guards LDS reuse
        buf ^= 1;
    }
#undef STAGE

    // epilogue: D[row = g + 4*i][col = r] per 16x16 tile (f64 reg-strided)
    #pragma unroll
    for (int nt = 0; nt < 4; ++nt) {
        const int col = wn * 64 + nt * 16 + r;
        const double bi = (double)bias[col];
        #pragma unroll
        for (int mt = 0; mt < 4; ++mt) {
            #pragma unroll
            for (int i = 0; i < 4; ++i) {
                const int row = wm * 64 + mt * 16 + g + 4 * i;
                O[(size_t)(mbase + row) * NSTK + wsel * DP + col] =
                    (float)(acc[mt][nt][i] + bi);
            }
        }
    }
}

// ---------------------------------------------------------------------------
// Kernel 2: attention per (b,h), all math in f64.
// ---------------------------------------------------------------------------
__global__ __launch_bounds__(256) void attn_kernel(
    const float* __restrict__ QKV,
    float* __restrict__ scores_out,  // [B][S][H] f32
    float* __restrict__ attnw_out,   // [B][S][H] f32
    double* __restrict__ wsrelu)     // [B][H][DP] f64
{
    const int b = blockIdx.x >> 2;
    const int h = blockIdx.x & 3;
    const int tid = threadIdx.x;
    const int wave = tid >> 6, lane = tid & 63;

    __shared__ double sc[SEQ];
    __shared__ double red[4];
    __shared__ double wacc[2][DP];

    const double scale = 0.08838834764831843;  // 1/sqrt(128) (f64)
    const float* base = QKV + (size_t)b * SEQ * NSTK;

    // scores: one wave per s
    for (int s = wave; s < SEQ; s += 4) {
        const float* row = base + (size_t)s * NSTK;
        const float2 qv = *reinterpret_cast<const float2*>(row + 256 + h * DP + lane * 2);
        const float2 kv = *reinterpret_cast<const float2*>(row + lane * 2);
        double p = (double)qv.x * (double)kv.x + (double)qv.y * (double)kv.y;
        #pragma unroll
        for (int o = 32; o; o >>= 1) p += __shfl_xor(p, o);
        p *= scale;
        if (lane == 0) {
            sc[s] = p;
            scores_out[((size_t)b * SEQ + s) * NH + h] = (float)p;
        }
    }
    __syncthreads();

    // softmax max
    double mx = -1e300;
    for (int i = tid; i < SEQ; i += 256) mx = fmax(mx, sc[i]);
    #pragma unroll
    for (int o = 32; o; o >>= 1) mx = fmax(mx, __shfl_xor(mx, o));
    if (lane == 0) red[wave] = mx;
    __syncthreads();
    mx = fmax(fmax(red[0], red[1]), fmax(red[2], red[3]));
    __syncthreads();

    double lsum = 0.0;
    for (int i = tid; i < SEQ; i += 256) {
        const double e = exp(sc[i] - mx);
        sc[i] = e;
        lsum += e;
    }
    #pragma unroll
    for (int o = 32; o; o >>= 1) lsum += __shfl_xor(lsum, o);
    if (lane == 0) red[wave] = lsum;
    __syncthreads();
    const double inv = 1.0 / (red[0] + red[1] + red[2] + red[3]);
    __syncthreads();
    for (int i = tid; i < SEQ; i += 256) {
        const double p = sc[i] * inv;
        sc[i] = p;
        attnw_out[((size_t)b * SEQ + i) * NH + h] = (float)p;
    }
    __syncthreads();

    // ws[p] = sum_s p_attn[s] * vals[s][p]
    const int p_idx = tid & 127, half = tid >> 7;
    double acc = 0.0;
    for (int s = half; s < SEQ; s += 2)
        acc = fma(sc[s], (double)base[(size_t)s * NSTK + 128 + p_idx], acc);
    wacc[half][p_idx] = acc;
    __syncthreads();
    if (tid < DP) {
        const double w = wacc[0][tid] + wacc[1][tid];
        wsrelu[((size_t)b * NH + h) * DP + tid] = fmax(w, 0.0);
    }
}

// ---------------------------------------------------------------------------
// Kernel 3a: logits[bh][c] = relu_ws . Wc[c] + bc[c] (f64); per-row mean/std.
// ---------------------------------------------------------------------------
__global__ __launch_bounds__(256) void logits_kernel(
    const double* __restrict__ wsrelu, const float* __restrict__ Wc,
    const float* __restrict__ bc, double* __restrict__ logits,
    double* __restrict__ stats)
{
    const int bh = blockIdx.x;
    const int tid = threadIdx.x;
    const int wave = tid >> 6, lane = tid & 63;
    __shared__ double w4s[DP];
    __shared__ double red[4];
    if (tid < DP) w4s[tid] = wsrelu[(size_t)bh * DP + tid];
    __syncthreads();

    double lsum = 0.0;
    for (int c = tid; c < NC; c += 256) {
        const float4* wr = reinterpret_cast<const float4*>(Wc + (size_t)c * DP);
        double acc = 0.0;
        #pragma unroll
        for (int k = 0; k < 32; ++k) {
            const float4 v = wr[k];
            acc = fma((double)v.x, w4s[4 * k + 0], acc);
            acc = fma((double)v.y, w4s[4 * k + 1], acc);
            acc = fma((double)v.z, w4s[4 * k + 2], acc);
            acc = fma((double)v.w, w4s[4 * k + 3], acc);
        }
        acc += (double)bc[c];
        logits[(size_t)bh * NC + c] = acc;
        lsum += acc;
    }
    #pragma unroll
    for (int o = 32; o; o >>= 1) lsum += __shfl_xor(lsum, o);
    if (lane == 0) red[wave] = lsum;
    __syncthreads();
    const double mean = (red[0] + red[1] + red[2] + red[3]) / (double)NC;
    __syncthreads();

    double lss = 0.0;
    for (int c = tid; c < NC; c += 256) {
        const double d = logits[(size_t)bh * NC + c] - mean;
        lss = fma(d, d, lss);
    }
    #pragma unroll
    for (int o = 32; o; o >>= 1) lss += __shfl_xor(lss, o);
    if (lane == 0) red[wave] = lss;
    __syncthreads();
    if (tid == 0) {
        const double var = (red[0] + red[1] + red[2] + red[3]) / (double)(NC - 1);
        stats[bh * 2 + 0] = mean;
        stats[bh * 2 + 1] = sqrt(var);
    }
}

// ---------------------------------------------------------------------------
// Kernel 3b: LN + max/argmax over heads + sigmoid, f64 compare path.
// ---------------------------------------------------------------------------
__global__ __launch_bounds__(256) void finalize_kernel(
    const double* __restrict__ logits, const double* __restrict__ stats,
    const float* __restrict__ ln_a, const float* __restrict__ ln_b,
    float* __restrict__ vid_probs, float* __restrict__ attn_idc)
{
    const int c = blockIdx.x * 256 + threadIdx.x;
    const int b = blockIdx.y;
    if (c >= NC) return;
    const double a = (double)ln_a[c], bb = (double)ln_b[c];
    double best = -1e300;
    int bi = 0;
    #pragma unroll
    for (int h = 0; h < NH; ++h) {
        const int bh = b * NH + h;
        const double x = logits[(size_t)bh * NC + c];
        const double ln = a * (x - stats[bh * 2]) / (stats[bh * 2 + 1] + 1e-6) + bb;
        if (ln > best) { best = ln; bi = h; }
    }
    vid_probs[(size_t)b * NC + c] = (float)(1.0 / (1.0 + exp(-best)));
    attn_idc[(size_t)b * NC + c] = (float)bi;
}

// ---------------------------------------------------------------------------
// Kernel 4: conv regularizer loss (Wc, bc only), f64. One block.
// ---------------------------------------------------------------------------
__global__ __launch_bounds__(256) void convloss_kernel(
    const float* __restrict__ Wc, const float* __restrict__ bc,
    float* __restrict__ out)
{
    __shared__ double t[NC];
    __shared__ double red[4];
    const int tid = threadIdx.x;
    const int wave = tid >> 6, lane = tid & 63;

    double lmax = -1e300;
    for (int c = tid; c < NC; c += 256) {
        const float4* wr = reinterpret_cast<const float4*>(Wc + (size_t)c * DP);
        double acc = 0.0;
        #pragma unroll
        for (int k = 0; k < 32; ++k) {
            const float4 v = wr[k];
            acc += (double)v.x + (double)v.y + (double)v.z + (double)v.w;
        }
        acc += (double)bc[c];
        t[c] = acc;
        lmax = fmax(lmax, acc);
    }
    #pragma unroll
    for (int o = 32; o; o >>= 1) lmax = fmax(lmax, __shfl_xor(lmax, o));
    if (lane == 0) red[wave] = lmax;
    __syncthreads();
    const double mx = fmax(fmax(red[0], red[1]), fmax(red[2], red[3]));
    __syncthreads();

    double lsum = 0.0;
    for (int c = tid; c < NC; c += 256) {
        const double e = exp(t[c] - mx);
        t[c] = e;
        lsum += e;
    }
    #pragma unroll
    for (int o = 32; o; o >>= 1) lsum += __shfl_xor(lsum, o);
    if (lane == 0) red[wave] = lsum;
    __syncthreads();
    const double inv = 1.0 / (red[0] + red[1] + red[2] + red[3]);
    __syncthreads();

    double psum = 0.0;
    for (int c = tid; c < NC; c += 256) {
        const double p = t[c] * inv;
        t[c] = p;
        psum += p;
    }
    #pragma unroll
    for (int o = 32; o; o >>= 1) psum += __shfl_xor(psum, o);
    if (lane == 0) red[wave] = psum;
    __syncthreads();
    const double mean = (red[0] + red[1] + red[2] + red[3]) / (double)NC;
    __syncthreads();

    double lss = 0.0;
    for (int c = tid; c < NC; c += 256) {
        const double d = t[c] - mean;
        lss = fma(d, d, lss);
    }
    #pragma unroll
    for (int o = 32; o; o >>= 1) lss += __shfl_xor(lss, o);
    if (lane == 0) red[wave] = lss;
    __syncthreads();
    if (tid == 0) {
        double stdv = sqrt((red[0] + red[1] + red[2] + red[3]) / (double)(NC - 1));
        stdv = fmin(fmax(stdv, 1e-9), 1e9);
        out[0] = (float)((double)BATCH * stdv);
    }
}

// ---------------------------------------------------------------------------
extern "C" void kernel_launch(void* const* d_in, const int* in_sizes, int n_in,
                              void* d_out, int out_size, void* d_ws, size_t ws_size,
                              hipStream_t stream)
{
    (void)in_sizes; (void)n_in; (void)out_size; (void)ws_size;
    const float* seg  = (const float*)d_in[0];
    const float* Wq   = (const float*)d_in[1];
    const float* bq   = (const float*)d_in[2];
    const float* Wk   = (const float*)d_in[3];
    const float* bk   = (const float*)d_in[4];
    const float* Wv   = (const float*)d_in[5];
    const float* bv   = (const float*)d_in[6];
    const float* Wc   = (const float*)d_in[7];
    const float* bc   = (const float*)d_in[8];
    const float* ln_a = (const float*)d_in[9];
    const float* ln_b = (const float*)d_in[10];

    float* out = (float*)d_out;
    float* vid_probs = out;                           // 64*3862
    float* attn_idc  = out + (size_t)BATCH * NC;      // 64*3862
    float* scores    = attn_idc + (size_t)BATCH * NC; // 64*300*4
    float* attnw     = scores + (size_t)BATCH * SEQ * NH;
    float* convl     = attnw + (size_t)BATCH * SEQ * NH;

    char* wsp = (char*)d_ws;
    float*  QKV    = (float*)wsp;                              // 19200*768 f32 (59.0 MB)
    wsp += (size_t)MROWS * NSTK * sizeof(float);
    double* wsrelu = (double*)wsp;                             // 256*128 f64
    wsp += (size_t)BATCH * NH * DP * sizeof(double);
    double* logits = (double*)wsp;                             // 256*3862 f64 (7.9 MB)
    wsp += (size_t)BATCH * NH * NC * sizeof(double);
    double* stats  = (double*)wsp;                             // 256*2 f64

    dim3 g1(MROWS / BM, NSTK / BN);   // (150, 6)
    proj_gemm_mfma<<<g1, 256, 0, stream>>>(seg, Wk, bk, Wv, bv, Wq, bq, QKV);

    attn_kernel<<<BATCH * NH, 256, 0, stream>>>(QKV, scores, attnw, wsrelu);

    logits_kernel<<<BATCH * NH, 256, 0, stream>>>(wsrelu, Wc, bc, logits, stats);

    dim3 g3((NC + 255) / 256, BATCH);
    finalize_kernel<<<g3, 256, 0, stream>>>(logits, stats, ln_a, ln_b, vid_probs, attn_idc);

    convloss_kernel<<<1, 256, 0, stream>>>(Wc, bc, convl);
}